// Round 3
// baseline (726.505 us; speedup 1.0000x reference)
//
#include <hip/hip_runtime.h>

#define D_MODEL  768
#define NHEAD    12
#define HEAD_DIM 64
#define SEQ      1024
#define BATCH    8
#define NTOK     8192

typedef unsigned short u16;
typedef unsigned int   u32;
typedef float  f32x4  __attribute__((ext_vector_type(4)));
typedef __bf16 bf16x8 __attribute__((ext_vector_type(8)));

#define MFMA(a, b, c) __builtin_amdgcn_mfma_f32_16x16x32_bf16((a), (b), (c), 0, 0, 0)

__device__ __forceinline__ u16 f2bf(float f) {          // RNE float->bf16
    u32 u = __float_as_uint(f);
    u += 0x7fffu + ((u >> 16) & 1u);
    return (u16)(u >> 16);
}
__device__ __forceinline__ u32 pack2(float a, float b) {
    return (u32)f2bf(a) | ((u32)f2bf(b) << 16);
}
__device__ __forceinline__ bf16x8 ldfrag(const u16* p) { // 16B-aligned LDS read
    union { uint4 u; bf16x8 b; } c;
    c.u = *(const uint4*)p;
    return c.b;
}
__device__ __forceinline__ bf16x8 u2b(uint4 u) {
    union { uint4 u; bf16x8 b; } c;
    c.u = u;
    return c.b;
}
__device__ __forceinline__ float bflo(u32 u) { return __uint_as_float(u << 16); }
__device__ __forceinline__ float bfhi(u32 u) { return __uint_as_float(u & 0xffff0000u); }

// async global->LDS, 16B per lane; lds base must be wave-uniform
__device__ __forceinline__ void gload16(const u16* g, u16* l) {
    __builtin_amdgcn_global_load_lds(
        (const __attribute__((address_space(1))) u32*)(const void*)g,
        (__attribute__((address_space(3))) u32*)(void*)l, 16, 0, 0);
}
__device__ __forceinline__ void bar() {
    asm volatile("" ::: "memory");
    __builtin_amdgcn_s_barrier();
    asm volatile("" ::: "memory");
}

// ---------------------------------------------------------------------------
// Kernel 0: one-shot fp32 -> bf16 convert of x and Wq/Wk/Wv (RNE, identical
// rounding to the old in-loop pack).  Exactly covers NX + 3*NW elems,
// 8 per thread; 3936 blocks * 256 threads * 8 == total (no tail).
// ---------------------------------------------------------------------------
__global__ __launch_bounds__(256)
void cvt_bf16(const float* __restrict__ x,  const float* __restrict__ Wq,
              const float* __restrict__ Wk, const float* __restrict__ Wv,
              u16* __restrict__ xb, u16* __restrict__ wb)
{
    const size_t NX = (size_t)NTOK * D_MODEL;      // 6291456
    const size_t NW = (size_t)D_MODEL * D_MODEL;   // 589824
    const size_t i  = ((size_t)blockIdx.x * 256 + threadIdx.x) * 8;
    const float* src; u16* dst; size_t off;
    if (i < NX) { src = x; dst = xb; off = i; }
    else {
        const size_t j = i - NX;
        const int zz = (int)(j / NW);
        off = j - (size_t)zz * NW;
        src = (zz == 0) ? Wq : (zz == 1) ? Wk : Wv;
        dst = wb + (size_t)zz * NW;
    }
    const float4 a = *(const float4*)(src + off);
    const float4 c = *(const float4*)(src + off + 4);
    uint4 o;
    o.x = pack2(a.x, a.y); o.y = pack2(a.z, a.w);
    o.z = pack2(c.x, c.y); o.w = pack2(c.z, c.w);
    *(uint4*)(dst + off) = o;
}

// ---------------------------------------------------------------------------
// Kernel 1: QKV projection, m97 structure: 128x128 tile, BK=64, 4 waves each
// owning 64x64 (4x4 frags of 16x16x32), global_load_lds width=16 into linear
// LDS [128][64].  K-iteration order (kt64 asc, ks32 asc) identical to the
// previous kernel -> bitwise-identical q/k/v outputs.
// LDS chunk map: thread t, chunk i -> LDS byte t*16 + i*4096
//   = row (t>>3)+32i (128B rows), colbyte (t&7)*16.
// ---------------------------------------------------------------------------
__global__ __launch_bounds__(256)
void qkv_gemm(const u16* __restrict__ xb, const u16* __restrict__ wb,
              const float* __restrict__ bq, const float* __restrict__ bk,
              const float* __restrict__ bv,
              u16* __restrict__ qo, u16* __restrict__ ko, u16* __restrict__ vto)
{
    const int m0 = blockIdx.x * 128;
    const int n0 = blockIdx.y * 128;
    const int z  = blockIdx.z;
    const u16*   W    = wb + (size_t)z * (D_MODEL * D_MODEL);
    const float* bias = (z == 0) ? bq : (z == 1) ? bk : bv;

    __shared__ u16 As[128 * 64];
    __shared__ u16 Bs[128 * 64];

    const int t    = threadIdx.x;
    const int lane = t & 63, wave = t >> 6;
    const int grp  = lane >> 4, l16 = lane & 15;
    const int wm   = (wave >> 1) * 64;
    const int wn   = (wave & 1) * 64;
    const int sr   = t >> 3;          // global row within tile for staging
    const int sc   = (t & 7) * 8;     // global col (elems) within K-slab

    const u16* ga = xb + (size_t)(m0 + sr) * D_MODEL + sc;
    const u16* gb = W  + (size_t)(n0 + sr) * D_MODEL + sc;
    u16* lA = As + wave * 512;        // + i*2048 (u16 units) per chunk
    u16* lB = Bs + wave * 512;

    f32x4 acc[4][4] = {};

    for (int kt = 0; kt < D_MODEL; kt += 64) {
        __syncthreads();              // prev iter's LDS reads done
#pragma unroll
        for (int i = 0; i < 4; ++i) {
            gload16(ga + (size_t)(i * 32) * D_MODEL + kt, lA + i * 2048);
            gload16(gb + (size_t)(i * 32) * D_MODEL + kt, lB + i * 2048);
        }
        __syncthreads();              // drains vmcnt (compiler) -> staged
#pragma unroll
        for (int ks = 0; ks < 64; ks += 32) {
            bf16x8 af[4], bfr[4];
#pragma unroll
            for (int m = 0; m < 4; ++m)
                af[m] = ldfrag(&As[(wm + m * 16 + l16) * 64 + ks + grp * 8]);
#pragma unroll
            for (int n = 0; n < 4; ++n)
                bfr[n] = ldfrag(&Bs[(wn + n * 16 + l16) * 64 + ks + grp * 8]);
#pragma unroll
            for (int m = 0; m < 4; ++m)
#pragma unroll
                for (int n = 0; n < 4; ++n)
                    acc[m][n] = MFMA(af[m], bfr[n], acc[m][n]);
        }
    }

    u16* qk_out = (z == 0) ? qo : ko;
#pragma unroll
    for (int n = 0; n < 4; ++n) {
        const int col = n0 + wn + n * 16 + l16;
        const float bcol = bias[col];
#pragma unroll
        for (int m = 0; m < 4; ++m) {
#pragma unroll
            for (int r = 0; r < 4; ++r) {
                const int row = m0 + wm + m * 16 + grp * 4 + r;
                const u16 hv = f2bf(acc[m][n][r] + bcol);
                if (z < 2) {
                    qk_out[(size_t)row * D_MODEL + col] = hv;
                } else {
                    const int hh = col >> 6, dd = col & 63;
                    const int bb = row >> 10, ss = row & 1023;
                    vto[(((size_t)(bb * NHEAD + hh)) * HEAD_DIM + dd) * SEQ + ss] = hv;
                }
            }
        }
    }
}

// ---------------------------------------------------------------------------
// Kernel 2: attention, single QK^T pass + register-buffered normalized-store
// sweep (round 2 structure), now with T14 prefetch + raw s_barrier so the
// kt+1 K/V global loads stay in flight across compute(kt) (no compiler
// vmcnt(0) drain at barriers).
// ---------------------------------------------------------------------------
__global__ __launch_bounds__(256, 2)
void attn_mfma(const u16* __restrict__ qb, const u16* __restrict__ kb,
               const u16* __restrict__ vtb, float* __restrict__ hout,
               float* __restrict__ sout)
{
    const int qt = blockIdx.x, h = blockIdx.y, b = blockIdx.z;
    const int t    = threadIdx.x;
    const int lane = t & 63, wave = t >> 6;
    const int grp  = lane >> 4, l16 = lane & 15;

    __shared__ u16 Qs[64][72];
    __shared__ u16 Ks[64][72];
    __shared__ u16 Vts[64][72];
    __shared__ u16 Ps[4][16][40];

    const size_t tok0 = (size_t)b * SEQ + qt * 64;
    const int    hb   = h * HEAD_DIM;
    const int    lr   = t >> 3, c0 = (t & 7) * 8;

    const u16* kbase = kb + (size_t)b * SEQ * D_MODEL + hb;
    const u16* vbase = vtb + ((size_t)(b * NHEAD + h) * HEAD_DIM + lr) * SEQ;

    // ---- issue kt=0 K/V loads (overlap with Q staging) ----
    uint4 pk0, pk1, pv0, pv1;
    {
        const u16* kp = kbase + (size_t)lr * D_MODEL + c0;
        pk0 = *(const uint4*)kp;
        pk1 = *(const uint4*)(kp + (size_t)32 * D_MODEL);
        const u16* vp = vbase + c0;
        pv0 = *(const uint4*)vp;
        pv1 = *(const uint4*)(vp + (size_t)32 * SEQ);
    }

    // ---- stage Q (once) ----
    {
        const u16* qp = qb + (tok0 + lr) * D_MODEL + hb + c0;
        const uint4 v0 = *(const uint4*)qp;
        const uint4 v1 = *(const uint4*)(qp + (size_t)32 * D_MODEL);
        *(uint4*)&Qs[lr][c0]      = v0;
        *(uint4*)&Qs[lr + 32][c0] = v1;
    }
    __syncthreads();
    const bf16x8 qa0 = ldfrag(&Qs[wave * 16 + l16][grp * 8]);
    const bf16x8 qa1 = ldfrag(&Qs[wave * 16 + l16][32 + grp * 8]);

    // ---- stage kt=0 tile ----
    *(uint4*)&Ks[lr][c0]       = pk0;
    *(uint4*)&Ks[lr + 32][c0]  = pk1;
    *(uint4*)&Vts[lr][c0]      = pv0;
    *(uint4*)&Vts[lr + 32][c0] = pv1;
    asm volatile("s_waitcnt lgkmcnt(0)" ::: "memory");
    bar();

    const float scale = 0.125f;
    float ssum[4] = {0.f, 0.f, 0.f, 0.f};
    f32x4 accO[4] = {};
    uint4 preg[32];                 // p~ bf16, A-layout, static indices

#pragma unroll
    for (int kt = 0; kt < 16; ++kt) {
        // issue kt+1 loads; in flight across compute (no barrier drain)
        if (kt < 15) {
            const u16* kp = kbase + (size_t)((kt + 1) * 64 + lr) * D_MODEL + c0;
            pk0 = *(const uint4*)kp;
            pk1 = *(const uint4*)(kp + (size_t)32 * D_MODEL);
            const u16* vp = vbase + (kt + 1) * 64 + c0;
            pv0 = *(const uint4*)vp;
            pv1 = *(const uint4*)(vp + (size_t)32 * SEQ);
        }
        // ---- compute tile kt ----
#pragma unroll
        for (int half = 0; half < 2; ++half) {
#pragma unroll
            for (int sub = 0; sub < 2; ++sub) {
                const int ti = half * 2 + sub;
                const bf16x8 kb0 = ldfrag(&Ks[ti * 16 + l16][grp * 8]);
                const bf16x8 kb1 = ldfrag(&Ks[ti * 16 + l16][32 + grp * 8]);
                f32x4 c = {0.f, 0.f, 0.f, 0.f};
                c = MFMA(qa0, kb0, c);
                c = MFMA(qa1, kb1, c);
#pragma unroll
                for (int r = 0; r < 4; ++r) {
                    const float p = __expf(c[r] * scale);   // unnormalized
                    ssum[r] += p;
                    Ps[wave][grp * 4 + r][sub * 16 + l16] = f2bf(p);
                }
            }
            // wave-private C-layout -> A-layout transpose
            const uint4 pw = *(const uint4*)&Ps[wave][l16][grp * 8];
            preg[kt * 2 + half] = pw;
            const bf16x8 pa = u2b(pw);
#pragma unroll
            for (int c4 = 0; c4 < 4; ++c4) {
                const bf16x8 vb = ldfrag(&Vts[c4 * 16 + l16][half * 32 + grp * 8]);
                accO[c4] = MFMA(pa, vb, accO[c4]);
            }
        }
        // ---- stage tile kt+1 ----
        if (kt < 15) {
            bar();                               // all waves done reading
            *(uint4*)&Ks[lr][c0]       = pk0;    // vmcnt waits auto-inserted
            *(uint4*)&Ks[lr + 32][c0]  = pk1;
            *(uint4*)&Vts[lr][c0]      = pv0;
            *(uint4*)&Vts[lr + 32][c0] = pv1;
            asm volatile("s_waitcnt lgkmcnt(0)" ::: "memory");
            bar();                               // staged
        }
    }

    // ---- row sums -> sinv ----
#pragma unroll
    for (int off = 1; off < 16; off <<= 1)
#pragma unroll
        for (int r = 0; r < 4; ++r) ssum[r] += __shfl_xor(ssum[r], off);
    float sinv[4];
#pragma unroll
    for (int r = 0; r < 4; ++r) sinv[r] = 1.0f / ssum[r];

    // sinv for row l16 (A-layout rows)
    const int src = (l16 >> 2) * 16 + l16;
    const float t0 = __shfl(ssum[0], src), t1 = __shfl(ssum[1], src);
    const float t2 = __shfl(ssum[2], src), t3 = __shfl(ssum[3], src);
    const float sa = (l16 & 1) ? t1 : t0;
    const float sb = (l16 & 1) ? t3 : t2;
    const float sinvrow = 1.0f / ((l16 & 2) ? sb : sa);

    // ---- h epilogue ----
#pragma unroll
    for (int c4 = 0; c4 < 4; ++c4)
#pragma unroll
        for (int r = 0; r < 4; ++r)
            hout[(tok0 + wave * 16 + grp * 4 + r) * D_MODEL + hb + c4 * 16 + l16] =
                accO[c4][r] * sinv[r];

    // ---- pure store sweep of normalized scores ----
    float* sp = sout + (size_t)(b * NHEAD + h) * SEQ * SEQ
              + (size_t)(qt * 64 + wave * 16 + l16) * SEQ + grp * 8;
#pragma unroll
    for (int kt = 0; kt < 16; ++kt) {
#pragma unroll
        for (int half = 0; half < 2; ++half) {
            const uint4 pw = preg[kt * 2 + half];
            float4 o0, o1;
            o0.x = bflo(pw.x) * sinvrow; o0.y = bfhi(pw.x) * sinvrow;
            o0.z = bflo(pw.y) * sinvrow; o0.w = bfhi(pw.y) * sinvrow;
            o1.x = bflo(pw.z) * sinvrow; o1.y = bfhi(pw.z) * sinvrow;
            o1.z = bflo(pw.w) * sinvrow; o1.w = bfhi(pw.w) * sinvrow;
            *(float4*)(sp + kt * 64 + half * 32)     = o0;
            *(float4*)(sp + kt * 64 + half * 32 + 4) = o1;
        }
    }
}

extern "C" void kernel_launch(void* const* d_in, const int* in_sizes, int n_in,
                              void* d_out, int out_size, void* d_ws, size_t ws_size,
                              hipStream_t stream)
{
    const float* x  = (const float*)d_in[0];
    const float* Wq = (const float*)d_in[1];
    const float* bq = (const float*)d_in[2];
    const float* Wk = (const float*)d_in[3];
    const float* bk = (const float*)d_in[4];
    const float* Wv = (const float*)d_in[5];
    const float* bv = (const float*)d_in[6];

    float* hout = (float*)d_out;                       // [8,1024,768]
    float* sout = hout + (size_t)NTOK * D_MODEL;       // [8,12,1024,1024]

    const size_t NX = (size_t)NTOK * D_MODEL;          // 6291456
    const size_t NW = (size_t)D_MODEL * D_MODEL;       // 589824

    u16* xb    = (u16*)d_ws;                           // [8192][768] bf16
    u16* wb    = xb + NX;                              // [3][768][768] bf16
    u16* qbuf  = wb + 3 * NW;                          // [8192][768] bf16
    u16* kbuf  = qbuf + NX;                            // [8192][768] bf16
    u16* vtbuf = kbuf + NX;                            // [8][12][64][1024] bf16

    cvt_bf16<<<dim3(3936), 256, 0, stream>>>(x, Wq, Wk, Wv, xb, wb);
    qkv_gemm<<<dim3(NTOK / 128, D_MODEL / 128, 3), 256, 0, stream>>>(
        xb, wb, bq, bk, bv, qbuf, kbuf, vtbuf);
    attn_mfma<<<dim3(SEQ / 64, NHEAD, BATCH), 256, 0, stream>>>(
        qbuf, kbuf, vtbuf, hout, sout);
}